// Round 3
// baseline (3336.288 us; speedup 1.0000x reference)
//
#include <hip/hip_runtime.h>

#define BATCH_N 16384
#define LDA 4608            // 9*512
#define PLANE 262144        // 512*512
typedef unsigned short ushort_t;
typedef __attribute__((ext_vector_type(4))) float f32x4;
typedef __attribute__((ext_vector_type(8))) short s16x8;
typedef __attribute__((ext_vector_type(4))) unsigned u32x4;

// truncating hi/lo bf16 split: v ~= hi + lo to ~2^-17 relative
__device__ __forceinline__ void split_bf(float f, ushort_t& h, ushort_t& l) {
    unsigned u = __float_as_uint(f);
    h = (ushort_t)(u >> 16);
    float r = f - __uint_as_float(u & 0xFFFF0000u);
    l = (ushort_t)(__float_as_uint(r) >> 16);
}
__device__ __forceinline__ unsigned pack_bf(float f) {
    unsigned u = __float_as_uint(f);
    float r = f - __uint_as_float(u & 0xFFFF0000u);
    return (u & 0xFFFF0000u) | (__float_as_uint(r) >> 16);
}
__device__ __forceinline__ float upack(unsigned u) {
    return __uint_as_float(u & 0xFFFF0000u) + __uint_as_float(u << 16);
}
__device__ __forceinline__ s16x8 mk8(const ushort_t* v) {
    return (s16x8){(short)v[0],(short)v[1],(short)v[2],(short)v[3],
                   (short)v[4],(short)v[5],(short)v[6],(short)v[7]};
}
// async global->LDS DMA, 16B per lane; lds dest = wave-uniform base + lane*16
typedef __attribute__((address_space(3))) unsigned as3_u32;
typedef __attribute__((address_space(1))) unsigned as1_u32;
__device__ __forceinline__ void dma16(const ushort_t* g, ushort_t* l) {
    __builtin_amdgcn_global_load_lds((as1_u32*)(unsigned long long)g,
                                     (as3_u32*)(unsigned)(unsigned long long)l,
                                     16, 0, 0);
}

// ---------------------------------------------------------------------------
// Weight convert: fp32 [n][k] -> hi/lo bf16 planes in the LDS tile image:
// chunk c = k>>5; dst = ((c*512 + n)*32 + (oct ^ (n&3))*8 + (k&7)) ushorts,
// oct = (k>>3)&3.  One thread per (plane, n, k-octet).
// ---------------------------------------------------------------------------
__global__ __launch_bounds__(256) void convert_w_k(
    const float* __restrict__ src, ushort_t* __restrict__ hi,
    ushort_t* __restrict__ lo, int total)
{
    const int gid = blockIdx.x * 256 + threadIdx.x;
    if (gid >= total) return;
    const int pp = gid >> 15;
    const int rem = gid & 32767;
    const int n = rem >> 6;
    const int o = rem & 63;
    const int chunk = o >> 2, oct = o & 3;
    const float* s = src + (size_t)pp * PLANE + (size_t)n * 512 + o * 8;
    const f32x4 f0 = *(const f32x4*)s;
    const f32x4 f1 = *(const f32x4*)(s + 4);
    ushort_t h[8], l[8];
#pragma unroll
    for (int e = 0; e < 4; ++e) {
        split_bf(f0[e], h[e], l[e]);
        split_bf(f1[e], h[4 + e], l[4 + e]);
    }
    const size_t d = (size_t)pp * PLANE + ((size_t)chunk * 512 + n) * 32
                   + (size_t)((oct ^ (n & 3)) * 8);
    *(s16x8*)&hi[d] = mk8(h);
    *(s16x8*)&lo[d] = mk8(l);
}

// ---------------------------------------------------------------------------
// Split-bf16 MFMA GEMM, block tile M=64 x N=512 (full row), 256 thr / 4 waves,
// wave tile 64x128, BK=32, B staged in two 256-col halves via global_load_lds.
// out[m][n] = sum_k A[m][k]*W[n][k] (+ epilogue)
//  EPI=0: outp[m*512+n] = acc + bias[n]                     (q)
//  EPI=1: logits[b][pz] = sum_n (acc+bias[n])*qv[b][n]      (no atomics)
//  EPI=2: row = l2norm(acc + bias + resid); packed in-place write to resid
// AFMT: A format 0=fp32 1=packed;  RFMT: resid format (EPI=2).
// ---------------------------------------------------------------------------
template<int EPI, int AFMT, int RFMT>
__global__ __launch_bounds__(256, 2) void gemm64_k(
    const void* Ap, int lda, int aoff0, int a_zstep,
    const ushort_t* __restrict__ Wh0, const ushort_t* __restrict__ Wl0,
    const float* __restrict__ bias0,
    float* __restrict__ outp,
    const float* __restrict__ qv, float* __restrict__ logits,
    void* resid, int rstride, int roff0)
{
    __shared__ ushort_t smem[20480];     // 40 KB
    ushort_t* Bh = smem;                 // 256 x 32 (half)
    ushort_t* Bl = smem + 8192;
    ushort_t* Ah = smem + 16384;         // 64 x 32
    ushort_t* Al = smem + 18432;

    const int t = threadIdx.x;
    const int lane = t & 63;
    const int w = t >> 6;                // wave 0..3
    const int quad = lane >> 4, l15 = lane & 15;
    const int b0 = blockIdx.x * 64;
    const int pz = blockIdx.z;
    const int aoff = aoff0 + pz * a_zstep;
    const ushort_t* Wh = Wh0 + (size_t)pz * PLANE;
    const ushort_t* Wl = Wl0 + (size_t)pz * PLANE;
    const float* bias = bias0 + pz * 512;

    // A staging: thread -> (row, k-octet)
    const int arow = t >> 2;             // 0..63
    const int aoct = t & 3;
    const size_t abase = (size_t)(b0 + arow) * lda + aoff + aoct * 8;
    const int adst = arow * 32 + ((aoct ^ (arow & 3)) * 8);

    f32x4 acc[4][8] = {};

    for (int c = 0; c < 16; ++c) {
        // global A -> regs (overlaps previous compute)
        ushort_t h8[8], l8[8];
        if (AFMT == 1) {
            const unsigned* Au = (const unsigned*)Ap;
            const u32x4 u0 = *(const u32x4*)(Au + abase + (size_t)c * 32);
            const u32x4 u1 = *(const u32x4*)(Au + abase + (size_t)c * 32 + 4);
#pragma unroll
            for (int e = 0; e < 4; ++e) {
                h8[e] = (ushort_t)(u0[e] >> 16); l8[e] = (ushort_t)u0[e];
                h8[4+e] = (ushort_t)(u1[e] >> 16); l8[4+e] = (ushort_t)u1[e];
            }
        } else {
            const float* Af = (const float*)Ap;
            const f32x4 f0 = *(const f32x4*)(Af + abase + (size_t)c * 32);
            const f32x4 f1 = *(const f32x4*)(Af + abase + (size_t)c * 32 + 4);
#pragma unroll
            for (int e = 0; e < 4; ++e) {
                split_bf(f0[e], h8[e], l8[e]);
                split_bf(f1[e], h8[4+e], l8[4+e]);
            }
        }
        s16x8 ah[4], av[4];
#pragma unroll
        for (int h = 0; h < 2; ++h) {
            __syncthreads();             // previous phase's LDS reads done
            {
                const size_t srow = ((size_t)c * 512 + h * 256 + w * 64) * 32
                                  + (size_t)lane * 8;
#pragma unroll
                for (int u = 0; u < 4; ++u) {
                    dma16(Wh + srow + u * 512, Bh + (w * 4 + u) * 512);
                    dma16(Wl + srow + u * 512, Bl + (w * 4 + u) * 512);
                }
            }
            if (h == 0) {
                *(s16x8*)&Ah[adst] = mk8(h8);
                *(s16x8*)&Al[adst] = mk8(l8);
            }
            __syncthreads();             // staging + DMA complete
            if (h == 0) {
#pragma unroll
                for (int i = 0; i < 4; ++i) {
                    const int rr = i * 16 + l15;
                    const int ao = rr * 32 + ((quad ^ (rr & 3)) * 8);
                    ah[i] = *(const s16x8*)&Ah[ao];
                    av[i] = *(const s16x8*)&Al[ao];
                }
            }
#pragma unroll
            for (int j2 = 0; j2 < 4; ++j2) {
                const int rn = w * 64 + j2 * 16 + l15;
                const int bo = rn * 32 + ((quad ^ (rn & 3)) * 8);
                const s16x8 bh = *(const s16x8*)&Bh[bo];
                const s16x8 bl = *(const s16x8*)&Bl[bo];
#pragma unroll
                for (int i = 0; i < 4; ++i) {
                    f32x4 a = acc[i][h * 4 + j2];
                    a = __builtin_amdgcn_mfma_f32_16x16x32_bf16(av[i], bh, a, 0, 0, 0);
                    a = __builtin_amdgcn_mfma_f32_16x16x32_bf16(ah[i], bl, a, 0, 0, 0);
                    a = __builtin_amdgcn_mfma_f32_16x16x32_bf16(ah[i], bh, a, 0, 0, 0);
                    acc[i][h * 4 + j2] = a;
                }
            }
        }
    }

    __syncthreads();                     // allow smem reuse for reductions
    float* red = (float*)smem;           // 64 x 4
    float* nrm = (float*)smem + 256;

    if (EPI == 0) {
#pragma unroll
        for (int i = 0; i < 4; ++i)
#pragma unroll
        for (int j = 0; j < 8; ++j) {
            const int n = (j >> 2) * 256 + w * 64 + (j & 3) * 16 + l15;
            const float bv = bias[n];
#pragma unroll
            for (int r = 0; r < 4; ++r) {
                const int m = i * 16 + quad * 4 + r;
                outp[(size_t)(b0 + m) * 512 + n] = acc[i][j][r] + bv;
            }
        }
    } else if (EPI == 1) {
        float rp[16];
#pragma unroll
        for (int v = 0; v < 16; ++v) rp[v] = 0.f;
#pragma unroll
        for (int j = 0; j < 8; ++j) {
            const int n = (j >> 2) * 256 + w * 64 + (j & 3) * 16 + l15;
            const float bv = bias[n];
#pragma unroll
            for (int i = 0; i < 4; ++i)
#pragma unroll
            for (int r = 0; r < 4; ++r) {
                const int m = i * 16 + quad * 4 + r;
                rp[i * 4 + r] += (acc[i][j][r] + bv) * qv[(size_t)(b0 + m) * 512 + n];
            }
        }
#pragma unroll
        for (int msk = 1; msk < 16; msk <<= 1)
#pragma unroll
            for (int v = 0; v < 16; ++v) rp[v] += __shfl_xor(rp[v], msk, 64);
        if (l15 == 0) {
#pragma unroll
            for (int i = 0; i < 4; ++i)
#pragma unroll
            for (int r = 0; r < 4; ++r)
                red[(i * 16 + quad * 4 + r) * 4 + w] = rp[i * 4 + r];
        }
        __syncthreads();
        if (t < 64)
            logits[(size_t)(b0 + t) * 9 + pz] =
                red[t * 4] + red[t * 4 + 1] + red[t * 4 + 2] + red[t * 4 + 3];
    } else {
        const int roffE = roff0 + pz * a_zstep;
        float rp[16];
#pragma unroll
        for (int v = 0; v < 16; ++v) rp[v] = 0.f;
#pragma unroll
        for (int j = 0; j < 8; ++j) {
            const int n = (j >> 2) * 256 + w * 64 + (j & 3) * 16 + l15;
            const float bv = bias[n];
#pragma unroll
            for (int i = 0; i < 4; ++i)
#pragma unroll
            for (int r = 0; r < 4; ++r) {
                const int m = i * 16 + quad * 4 + r;
                const size_t ridx = (size_t)(b0 + m) * rstride + roffE + n;
                const float rv = (RFMT == 1) ? upack(((const unsigned*)resid)[ridx])
                                             : ((const float*)resid)[ridx];
                const float v = acc[i][j][r] + bv + rv;
                acc[i][j][r] = v;
                rp[i * 4 + r] += v * v;
            }
        }
#pragma unroll
        for (int msk = 1; msk < 16; msk <<= 1)
#pragma unroll
            for (int v = 0; v < 16; ++v) rp[v] += __shfl_xor(rp[v], msk, 64);
        if (l15 == 0) {
#pragma unroll
            for (int i = 0; i < 4; ++i)
#pragma unroll
            for (int r = 0; r < 4; ++r)
                red[(i * 16 + quad * 4 + r) * 4 + w] = rp[i * 4 + r];
        }
        __syncthreads();
        if (t < 64) {
            const float s = red[t * 4] + red[t * 4 + 1] + red[t * 4 + 2] + red[t * 4 + 3];
            nrm[t] = 1.0f / fmaxf(sqrtf(s), 1e-12f);
        }
        __syncthreads();
        unsigned* xw = (unsigned*)resid;
#pragma unroll
        for (int i = 0; i < 4; ++i)
#pragma unroll
        for (int r = 0; r < 4; ++r) {
            const int m = i * 16 + quad * 4 + r;
            const float s = nrm[m];
#pragma unroll
            for (int j = 0; j < 8; ++j) {
                const int n = (j >> 2) * 256 + w * 64 + (j & 3) * 16 + l15;
                xw[(size_t)(b0 + m) * rstride + roffE + n] = pack_bf(acc[i][j][r] * s);
            }
        }
    }
}

// ---------------------------------------------------------------------------
// softmax over 9 logits + weighted sum (+final residual) + l2norm.
// MODE 0: write packed cent;  MODE 1: out = l2norm(cent + x[b,8,:]) fp32.
// ---------------------------------------------------------------------------
template<int XFMT, int MODE>
__global__ __launch_bounds__(256) void softmax_cent_k(
    const void* xg, const float* __restrict__ logits, void* outp)
{
    const int lane = threadIdx.x & 63;
    const size_t b = (size_t)blockIdx.x * 4 + (threadIdx.x >> 6);
    float lg[9], mx = -1e30f;
#pragma unroll
    for (int p = 0; p < 9; ++p) { lg[p] = logits[b * 9 + p]; mx = fmaxf(mx, lg[p]); }
    float s = 0.f;
#pragma unroll
    for (int p = 0; p < 9; ++p) { lg[p] = __expf(lg[p] - mx); s += lg[p]; }
    const float inv = 1.0f / s;
    float c[8];
    float ssq = 0.f;
#pragma unroll
    for (int v = 0; v < 2; ++v) {
        float a[4] = {0.f, 0.f, 0.f, 0.f};
        float x8[4] = {0.f, 0.f, 0.f, 0.f};
#pragma unroll
        for (int p = 0; p < 9; ++p) {
            float f[4];
            if (XFMT == 1) {
                const u32x4 u = ((const u32x4*)xg)[(size_t)(b * 9 + p) * 128 + v * 64 + lane];
#pragma unroll
                for (int e = 0; e < 4; ++e) f[e] = upack(u[e]);
            } else {
                const f32x4 xv = ((const f32x4*)xg)[(size_t)(b * 9 + p) * 128 + v * 64 + lane];
#pragma unroll
                for (int e = 0; e < 4; ++e) f[e] = xv[e];
            }
#pragma unroll
            for (int e = 0; e < 4; ++e) a[e] += lg[p] * f[e];
            if (MODE == 1 && p == 8) {
#pragma unroll
                for (int e = 0; e < 4; ++e) x8[e] = f[e];
            }
        }
#pragma unroll
        for (int e = 0; e < 4; ++e) {
            float av = a[e] * inv;
            if (MODE == 1) av += x8[e];
            c[v * 4 + e] = av;
            ssq += av * av;
        }
    }
#pragma unroll
    for (int off = 32; off > 0; off >>= 1) ssq += __shfl_xor(ssq, off, 64);
    const float invn = 1.0f / fmaxf(sqrtf(ssq), 1e-12f);
#pragma unroll
    for (int v = 0; v < 2; ++v) {
        if (MODE == 1) {
            f32x4 o;
#pragma unroll
            for (int e = 0; e < 4; ++e) o[e] = c[v * 4 + e] * invn;
            ((f32x4*)outp)[(size_t)b * 128 + v * 64 + lane] = o;
        } else {
            u32x4 o;
#pragma unroll
            for (int e = 0; e < 4; ++e) o[e] = pack_bf(c[v * 4 + e] * invn);
            ((u32x4*)outp)[(size_t)b * 128 + v * 64 + lane] = o;
        }
    }
}

// ---------------------------------------------------------------------------
extern "C" void kernel_launch(void* const* d_in, const int* in_sizes, int n_in,
                              void* d_out, int out_size, void* d_ws, size_t ws_size,
                              hipStream_t stream) {
    (void)in_sizes; (void)n_in; (void)out_size; (void)ws_size;
    float* x = (float*)d_in[0];   // mutated in place (packed hi/lo after layer 1)
    const float* Wq  = (const float*)d_in[1];
    const float* bq  = (const float*)d_in[2];
    const float* Wk  = (const float*)d_in[3];
    const float* bk  = (const float*)d_in[4];
    const float* Wfw = (const float*)d_in[5];
    const float* bfw = (const float*)d_in[6];
    const float* Wfc = (const float*)d_in[7];
    const float* bfc = (const float*)d_in[8];
    const float* Wqf = (const float*)d_in[9];
    const float* bqf = (const float*)d_in[10];
    const float* Wkf = (const float*)d_in[11];
    const float* bkf = (const float*)d_in[12];
    float* out = (float*)d_out;

    // ws: [whi | wlo | q fp32 | cent packed | logits]  ~138 MB
    ushort_t* whi = (ushort_t*)d_ws;
    ushort_t* wlo = whi + (size_t)67 * PLANE;
    float* q       = (float*)(wlo + (size_t)67 * PLANE);
    unsigned* cent = (unsigned*)(q + (size_t)BATCH_N * 512);
    float* logits  = (float*)(cent + (size_t)BATCH_N * 512);

    const size_t OWq = 0, OWk = 3, OWfw = 30, OWfc = 54, OWqf = 57, OWkf = 58;
    struct { const float* s; size_t off; int cnt; } cv[6] = {
        {Wq, OWq, 3}, {Wk, OWk, 27}, {Wfw, OWfw, 24},
        {Wfc, OWfc, 3}, {Wqf, OWqf, 1}, {Wkf, OWkf, 9}};
    for (int i = 0; i < 6; ++i)
        convert_w_k<<<cv[i].cnt * 128, 256, 0, stream>>>(
            cv[i].s, whi + cv[i].off * PLANE, wlo + cv[i].off * PLANE,
            cv[i].cnt * 32768);

    const dim3 g1(BATCH_N / 64, 1, 1);
    const dim3 g8(BATCH_N / 64, 1, 8);
    const dim3 g9(BATCH_N / 64, 1, 9);
    const int sg = BATCH_N / 4;

    for (int l = 0; l < 3; ++l) {
        const ushort_t* qh = whi + (OWq + l) * PLANE,  * ql = wlo + (OWq + l) * PLANE;
        const ushort_t* kh = whi + (OWk + (size_t)l * 9) * PLANE,
                      * kl = wlo + (OWk + (size_t)l * 9) * PLANE;
        const ushort_t* ch = whi + (OWfc + l) * PLANE, * cl = wlo + (OWfc + l) * PLANE;
        const ushort_t* fh = whi + (OWfw + (size_t)l * 8) * PLANE,
                      * fl = wlo + (OWfw + (size_t)l * 8) * PLANE;
        if (l == 0) {
            gemm64_k<0,0,0><<<g1,256,0,stream>>>(x, LDA, 8*512, 0, qh, ql,
                bq, q, nullptr, nullptr, nullptr, 0, 0);
            gemm64_k<1,0,0><<<g9,256,0,stream>>>(x, LDA, 0, 512, kh, kl,
                bk, nullptr, q, logits, nullptr, 0, 0);
            softmax_cent_k<0,0><<<sg,256,0,stream>>>(x, logits, cent);
            gemm64_k<2,1,0><<<g1,256,0,stream>>>(cent, 512, 0, 0, ch, cl,
                bfc, nullptr, nullptr, nullptr, x, LDA, 8*512);
            gemm64_k<2,0,0><<<g8,256,0,stream>>>(x, LDA, 0, 512, fh, fl,
                bfw, nullptr, nullptr, nullptr, x, LDA, 0);
        } else {
            gemm64_k<0,1,0><<<g1,256,0,stream>>>(x, LDA, 8*512, 0, qh, ql,
                bq + l*512, q, nullptr, nullptr, nullptr, 0, 0);
            gemm64_k<1,1,0><<<g9,256,0,stream>>>(x, LDA, 0, 512, kh, kl,
                bk + (size_t)l*9*512, nullptr, q, logits, nullptr, 0, 0);
            softmax_cent_k<1,0><<<sg,256,0,stream>>>(x, logits, cent);
            gemm64_k<2,1,1><<<g1,256,0,stream>>>(cent, 512, 0, 0, ch, cl,
                bfc + l*512, nullptr, nullptr, nullptr, x, LDA, 8*512);
            gemm64_k<2,1,1><<<g8,256,0,stream>>>(x, LDA, 0, 512, fh, fl,
                bfw + (size_t)l*8*512, nullptr, nullptr, nullptr, x, LDA, 0);
        }
    }
    // final attention -> out
    gemm64_k<0,1,0><<<g1,256,0,stream>>>(x, LDA, 8*512, 0,
        whi + OWqf*PLANE, wlo + OWqf*PLANE, bqf, q, nullptr, nullptr, nullptr, 0, 0);
    gemm64_k<1,1,0><<<g9,256,0,stream>>>(x, LDA, 0, 512,
        whi + OWkf*PLANE, wlo + OWkf*PLANE, bkf, nullptr, q, logits, nullptr, 0, 0);
    softmax_cent_k<1,1><<<sg,256,0,stream>>>(x, logits, out);
}